// Round 5
// baseline (77.638 us; speedup 1.0000x reference)
//
#include <hip/hip_runtime.h>
#include <stdint.h>

#define MM 8
#define KK 8192
#define NN 8192
#define KC 256                 // k rows per gemm block
#define KSPLIT (KK / KC)       // 32 partial slabs
#define G 8                    // software-pipeline group (k-steps per buffer)
#define FP8MAXV 448.0f

typedef float f32x4 __attribute__((ext_vector_type(4)));
typedef float f32x2 __attribute__((ext_vector_type(2)));

// ws layout (floats):
//   [0..7]                    x_scale_inv per row
//   [64 .. 64+KK*MM)          xqT transposed quantized activations [k][m]
//   [PART_OFF ..)             partials [KSPLIT][MM][NN]
#define XQT_OFF 64
#define PART_OFF (XQT_OFF + KK * MM)

// ---------------------------------------------------------------------------
// Bit-exact RNE f32 -> fp8 e4m3fn -> f32 (|v| <= 448).
// ---------------------------------------------------------------------------
__device__ __forceinline__ float fp8_e4m3_round(float v) {
    uint32_t u = __float_as_uint(v);
    uint32_t mag = u & 0x7fffffffu;
    if (mag >= 0x3C800000u) {            // |v| >= 2^-6 : normal e4m3
        uint32_t lsb = (u >> 20) & 1u;
        uint32_t r = u + 0x0007FFFFu + lsb;
        r &= 0xFFF00000u;
        return __uint_as_float(r);
    }
    return rintf(v * 512.0f) * (1.0f / 512.0f);   // subnormal quantum 2^-9
}

// ---------------------------------------------------------------------------
// Kernel 1: per-row amax -> scale; quantize x; store xqT[k][m].
// ---------------------------------------------------------------------------
__global__ __launch_bounds__(256) void prep_kernel(const float* __restrict__ x,
                                                   float* __restrict__ ws) {
    const int m = blockIdx.x;
    const int tid = threadIdx.x;
    const float* row = x + (size_t)m * KK;

    float amax = 0.0f;
    for (int k = tid * 4; k < KK; k += 256 * 4) {
        f32x4 v = *(const f32x4*)(row + k);
        amax = fmaxf(amax, fmaxf(fmaxf(fabsf(v.x), fabsf(v.y)),
                                 fmaxf(fabsf(v.z), fabsf(v.w))));
    }
#pragma unroll
    for (int off = 32; off >= 1; off >>= 1)
        amax = fmaxf(amax, __shfl_xor(amax, off, 64));

    __shared__ float sred[4];
    __shared__ float sscale;
    if ((tid & 63) == 0) sred[tid >> 6] = amax;
    __syncthreads();
    if (tid == 0) {
        float a = fmaxf(fmaxf(sred[0], sred[1]), fmaxf(sred[2], sred[3]));
        float scale = (a > 0.0f) ? (FP8MAXV / a) : 1.0f;
        sscale = scale;
        ws[m] = 1.0f / scale;
    }
    __syncthreads();
    const float scale = sscale;

    float* xqT = ws + XQT_OFF;
    for (int k = tid; k < KK; k += 256)
        xqT[(size_t)k * MM + m] = fp8_e4m3_round(row[k] * scale);
}

// ---------------------------------------------------------------------------
// Kernel 2: split-K GEMV partials. 2 columns/thread (f32x2 W loads, 512 B per
// wave-instr), KC=256, grid (NN/512, KSPLIT) = 512 blocks = 2/CU, 8 waves/CU.
// W loads explicitly double-buffered in registers (wA/wB, G=8) so >=8 loads
// (4 KB/wave) stay in flight through every compute phase. Activations read
// DIRECTLY from global with wave-uniform addresses -> scalar s_load path
// (no LDS, no barrier; VALU reads the SGPR operand for free).
// ---------------------------------------------------------------------------
__global__ __launch_bounds__(256, 2) void gemm_partial(const float* __restrict__ W,
                                                       const float* __restrict__ wsinv,
                                                       const float* __restrict__ ws,
                                                       float* __restrict__ part) {
    const int tid = threadIdx.x;
    const int n2  = (blockIdx.x * 256 + tid) * 2;
    const int c   = blockIdx.y;
    const int k0  = c * KC;

    const float* __restrict__ Wp = W + (size_t)k0 * NN + n2;
    const float* __restrict__ xq = ws + XQT_OFF + (size_t)k0 * MM;  // uniform

    f32x2 acc[MM];
#pragma unroll
    for (int m = 0; m < MM; ++m) acc[m] = (f32x2)0.0f;

    f32x2 wA[G], wB[G];

    auto loadg = [&](f32x2 (&buf)[G], int gbase) {
#pragma unroll
        for (int j = 0; j < G; ++j)
            buf[j] = *(const f32x2*)(Wp + (size_t)(gbase + j) * NN);
    };
    auto compute = [&](f32x2 (&buf)[G], int gbase) {
#pragma unroll
        for (int j = 0; j < G; ++j) {
            const float* a = xq + (size_t)(gbase + j) * MM;  // uniform -> s_load
            f32x2 w = buf[j];
            acc[0] += w * a[0];
            acc[1] += w * a[1];
            acc[2] += w * a[2];
            acc[3] += w * a[3];
            acc[4] += w * a[4];
            acc[5] += w * a[5];
            acc[6] += w * a[6];
            acc[7] += w * a[7];
        }
    };

    loadg(wA, 0 * G);
    loadg(wB, 1 * G);
    int g = 0;
    for (; g + 2 < KC / G; g += 2) {
        compute(wA, (g + 0) * G);
        loadg(wA, (g + 2) * G);
        compute(wB, (g + 1) * G);
        loadg(wB, (g + 3) * G);
    }
    compute(wA, (g + 0) * G);
    compute(wB, (g + 1) * G);

    const f32x2 wsn = *(const f32x2*)(wsinv + n2);
    float* p = part + ((size_t)c * MM) * NN + n2;
#pragma unroll
    for (int m = 0; m < MM; ++m)
        *(f32x2*)(p + (size_t)m * NN) = acc[m] * (ws[m] * wsn);
}

// ---------------------------------------------------------------------------
// Kernel 3: reduce KSPLIT partials + bias -> out. One thread per output.
// ---------------------------------------------------------------------------
__global__ __launch_bounds__(256) void reduce_kernel(const float* __restrict__ part,
                                                     const float* __restrict__ bias,
                                                     float* __restrict__ out) {
    const int idx = blockIdx.x * 256 + threadIdx.x;   // MM*NN threads
    float s = bias[idx & (NN - 1)];
#pragma unroll
    for (int c = 0; c < KSPLIT; ++c)
        s += part[(size_t)c * MM * NN + idx];
    out[idx] = s;
}

// ---------------------------------------------------------------------------
// Fallback path (only if ws too small): bias-init + atomic gemm.
// ---------------------------------------------------------------------------
__global__ __launch_bounds__(256) void init_kernel(const float* __restrict__ bias,
                                                   float* __restrict__ out) {
    int idx = blockIdx.x * 256 + threadIdx.x;
    out[idx] = bias[idx & (NN - 1)];
}

__global__ __launch_bounds__(256, 2) void gemm_atomic(const float* __restrict__ W,
                                                      const float* __restrict__ wsinv,
                                                      const float* __restrict__ ws,
                                                      float* __restrict__ out) {
    const int tid = threadIdx.x;
    const int n2  = (blockIdx.x * 256 + tid) * 2;
    const int k0  = blockIdx.y * KC;

    const float* __restrict__ Wp = W + (size_t)k0 * NN + n2;
    const float* __restrict__ xq = ws + XQT_OFF + (size_t)k0 * MM;

    f32x2 acc[MM];
#pragma unroll
    for (int m = 0; m < MM; ++m) acc[m] = (f32x2)0.0f;

    for (int k = 0; k < KC; ++k) {
        f32x2 w = *(const f32x2*)(Wp + (size_t)k * NN);
        const float* a = xq + (size_t)k * MM;
#pragma unroll
        for (int m = 0; m < MM; ++m) acc[m] += w * a[m];
    }

    const f32x2 wsn = *(const f32x2*)(wsinv + n2);
#pragma unroll
    for (int m = 0; m < MM; ++m) {
        f32x2 r = acc[m] * (ws[m] * wsn);
        unsafeAtomicAdd(out + (size_t)m * NN + n2 + 0, r.x);
        unsafeAtomicAdd(out + (size_t)m * NN + n2 + 1, r.y);
    }
}

extern "C" void kernel_launch(void* const* d_in, const int* in_sizes, int n_in,
                              void* d_out, int out_size, void* d_ws, size_t ws_size,
                              hipStream_t stream) {
    const float* x     = (const float*)d_in[0];   // [M,K] f32
    const float* W     = (const float*)d_in[1];   // [K,N] f32 (fp8 values)
    const float* wsinv = (const float*)d_in[2];   // [N]   f32
    const float* bias  = (const float*)d_in[3];   // [N]   f32
    float* out = (float*)d_out;                   // [M,N] f32
    float* ws  = (float*)d_ws;

    const size_t need = (size_t)(PART_OFF + (size_t)KSPLIT * MM * NN) * sizeof(float);

    prep_kernel<<<MM, 256, 0, stream>>>(x, ws);

    if (ws_size >= need) {
        float* part = ws + PART_OFF;
        gemm_partial<<<dim3(NN / 512, KSPLIT), 256, 0, stream>>>(W, wsinv, ws, part);
        reduce_kernel<<<(MM * NN) / 256, 256, 0, stream>>>(part, bias, out);
    } else {
        init_kernel<<<(MM * NN) / 256, 256, 0, stream>>>(bias, out);
        gemm_atomic<<<dim3(NN / 512, KSPLIT), 256, 0, stream>>>(W, wsinv, ws, out);
    }
}

// Round 6
// 72.139 us; speedup vs baseline: 1.0762x; 1.0762x over previous
//
#include <hip/hip_runtime.h>
#include <stdint.h>

#define MM 8
#define KK 8192
#define NN 8192
#define KC 128                 // k rows per gemm block
#define KSPLIT (KK / KC)       // 64 partial slabs
#define G 4                    // k-steps per prefetch group
#define FP8MAXV 448.0f

typedef float f32x4 __attribute__((ext_vector_type(4)));

// ws layout (floats):
//   [0..7]                    x_scale_inv per row
//   [64 .. 64+KK*MM)          xqT transposed quantized activations [k][m]
//   [PART_OFF ..)             partials [KSPLIT][MM][NN]  (16 MB)
#define XQT_OFF 64
#define PART_OFF (XQT_OFF + KK * MM)

// ---------------------------------------------------------------------------
// Bit-exact RNE f32 -> fp8 e4m3fn -> f32 (|v| <= 448).
// ---------------------------------------------------------------------------
__device__ __forceinline__ float fp8_e4m3_round(float v) {
    uint32_t u = __float_as_uint(v);
    uint32_t mag = u & 0x7fffffffu;
    if (mag >= 0x3C800000u) {            // |v| >= 2^-6 : normal e4m3
        uint32_t lsb = (u >> 20) & 1u;
        uint32_t r = u + 0x0007FFFFu + lsb;
        r &= 0xFFF00000u;
        return __uint_as_float(r);
    }
    return rintf(v * 512.0f) * (1.0f / 512.0f);   // subnormal quantum 2^-9
}

// ---------------------------------------------------------------------------
// Kernel 1: per-row amax -> scale; quantize x; store xqT[k][m].
// ---------------------------------------------------------------------------
__global__ __launch_bounds__(256) void prep_kernel(const float* __restrict__ x,
                                                   float* __restrict__ ws) {
    const int m = blockIdx.x;
    const int tid = threadIdx.x;
    const float* row = x + (size_t)m * KK;

    float amax = 0.0f;
    for (int k = tid * 4; k < KK; k += 256 * 4) {
        f32x4 v = *(const f32x4*)(row + k);
        amax = fmaxf(amax, fmaxf(fmaxf(fabsf(v.x), fabsf(v.y)),
                                 fmaxf(fabsf(v.z), fabsf(v.w))));
    }
#pragma unroll
    for (int off = 32; off >= 1; off >>= 1)
        amax = fmaxf(amax, __shfl_xor(amax, off, 64));

    __shared__ float sred[4];
    __shared__ float sscale;
    if ((tid & 63) == 0) sred[tid >> 6] = amax;
    __syncthreads();
    if (tid == 0) {
        float a = fmaxf(fmaxf(sred[0], sred[1]), fmaxf(sred[2], sred[3]));
        float scale = (a > 0.0f) ? (FP8MAXV / a) : 1.0f;
        sscale = scale;
        ws[m] = 1.0f / scale;
    }
    __syncthreads();
    const float scale = sscale;

    float* xqT = ws + XQT_OFF;
    for (int k = tid; k < KK; k += 256)
        xqT[(size_t)k * MM + m] = fp8_e4m3_round(row[k] * scale);
}

// ---------------------------------------------------------------------------
// Kernel 2: split-K GEMV partials. 4 cols/thread (dwordx4 W loads = 1 KiB per
// wave-instr). KC=128, grid (NN/1024, KSPLIT) = (8,64) = 512 blocks = 2/CU.
// W loads explicitly double-buffered in registers (wA/wB, G=4 -> 8 KiB/wave
// in flight). Activations staged once in LDS (4 KB) and read per-k as two
// ds_read_b128 broadcasts -> lgkmcnt path, never disturbs the vmcnt queue
// that paces the W stream (the R4 failure mode). LB(256,2) keeps VGPR cap at
// 256 so the compiler never starves the pipeline (the R2 failure mode).
// ---------------------------------------------------------------------------
__global__ __launch_bounds__(256, 2) void gemm_partial(const float* __restrict__ W,
                                                       const float* __restrict__ wsinv,
                                                       const float* __restrict__ ws,
                                                       float* __restrict__ part) {
    const int tid = threadIdx.x;
    const int n4  = (blockIdx.x * 256 + tid) * 4;
    const int c   = blockIdx.y;
    const int k0  = c * KC;

    __shared__ f32x4 sxq[KC * MM / 4];   // 4 KB: [k][half], half=0: m0..3, 1: m4..7
    sxq[tid] = ((const f32x4*)(ws + XQT_OFF + (size_t)k0 * MM))[tid];

    const f32x4 xs0 = *(const f32x4*)(ws);        // x_scale_inv[0..3]
    const f32x4 xs1 = *(const f32x4*)(ws + 4);    // x_scale_inv[4..7]
    const f32x4 wsn = *(const f32x4*)(wsinv + n4);
    __syncthreads();

    f32x4 acc[MM];
#pragma unroll
    for (int m = 0; m < MM; ++m) acc[m] = (f32x4)0.0f;

    const float* __restrict__ Wp = W + (size_t)k0 * NN + n4;

    f32x4 wA[G], wB[G];
    auto loadg = [&](f32x4 (&buf)[G], int kbase) {
#pragma unroll
        for (int j = 0; j < G; ++j)
            buf[j] = *(const f32x4*)(Wp + (size_t)(kbase + j) * NN);
    };
    auto compute = [&](f32x4 (&buf)[G], int kbase) {
#pragma unroll
        for (int j = 0; j < G; ++j) {
            f32x4 a0 = sxq[(kbase + j) * 2 + 0];   // ds_read_b128 broadcast
            f32x4 a1 = sxq[(kbase + j) * 2 + 1];
            f32x4 w  = buf[j];
            acc[0] += w * a0.x;
            acc[1] += w * a0.y;
            acc[2] += w * a0.z;
            acc[3] += w * a0.w;
            acc[4] += w * a1.x;
            acc[5] += w * a1.y;
            acc[6] += w * a1.z;
            acc[7] += w * a1.w;
        }
    };

    loadg(wA, 0 * G);
    loadg(wB, 1 * G);
    int g = 0;
    for (; g + 2 < KC / G; g += 2) {
        compute(wA, (g + 0) * G);
        loadg(wA, (g + 2) * G);
        compute(wB, (g + 1) * G);
        loadg(wB, (g + 3) * G);
    }
    compute(wA, (g + 0) * G);
    compute(wB, (g + 1) * G);

    float xsa[MM] = {xs0.x, xs0.y, xs0.z, xs0.w, xs1.x, xs1.y, xs1.z, xs1.w};
    float* p = part + ((size_t)c * MM) * NN + n4;
#pragma unroll
    for (int m = 0; m < MM; ++m)
        *(f32x4*)(p + (size_t)m * NN) = acc[m] * (xsa[m] * wsn);
}

// ---------------------------------------------------------------------------
// Kernel 3: reduce KSPLIT partials + bias -> out. One output/thread,
// 64 independent coalesced loads per thread (plenty of MLP), 256 blocks.
// ---------------------------------------------------------------------------
__global__ __launch_bounds__(256) void reduce_kernel(const float* __restrict__ part,
                                                     const float* __restrict__ bias,
                                                     float* __restrict__ out) {
    const int idx = blockIdx.x * 256 + threadIdx.x;   // MM*NN threads
    float s = bias[idx & (NN - 1)];
#pragma unroll 16
    for (int c = 0; c < KSPLIT; ++c)
        s += part[(size_t)c * (MM * NN) + idx];
    out[idx] = s;
}

// ---------------------------------------------------------------------------
// Fallback path (only if ws too small): bias-init + atomic gemm.
// ---------------------------------------------------------------------------
__global__ __launch_bounds__(256) void init_kernel(const float* __restrict__ bias,
                                                   float* __restrict__ out) {
    int idx = blockIdx.x * 256 + threadIdx.x;
    out[idx] = bias[idx & (NN - 1)];
}

__global__ __launch_bounds__(256, 2) void gemm_atomic(const float* __restrict__ W,
                                                      const float* __restrict__ wsinv,
                                                      const float* __restrict__ ws,
                                                      float* __restrict__ out) {
    const int tid = threadIdx.x;
    const int n4  = (blockIdx.x * 256 + tid) * 4;
    const int k0  = blockIdx.y * KC;

    __shared__ f32x4 sxq[KC * MM / 4];
    sxq[tid] = ((const f32x4*)(ws + XQT_OFF + (size_t)k0 * MM))[tid];
    const f32x4 xs0 = *(const f32x4*)(ws);
    const f32x4 xs1 = *(const f32x4*)(ws + 4);
    const f32x4 wsn = *(const f32x4*)(wsinv + n4);
    __syncthreads();

    f32x4 acc[MM];
#pragma unroll
    for (int m = 0; m < MM; ++m) acc[m] = (f32x4)0.0f;

    const float* __restrict__ Wp = W + (size_t)k0 * NN + n4;
    for (int k = 0; k < KC; ++k) {
        f32x4 w  = *(const f32x4*)(Wp + (size_t)k * NN);
        f32x4 a0 = sxq[k * 2 + 0];
        f32x4 a1 = sxq[k * 2 + 1];
        acc[0] += w * a0.x;  acc[1] += w * a0.y;
        acc[2] += w * a0.z;  acc[3] += w * a0.w;
        acc[4] += w * a1.x;  acc[5] += w * a1.y;
        acc[6] += w * a1.z;  acc[7] += w * a1.w;
    }

    float xsa[MM] = {xs0.x, xs0.y, xs0.z, xs0.w, xs1.x, xs1.y, xs1.z, xs1.w};
#pragma unroll
    for (int m = 0; m < MM; ++m) {
        f32x4 r = acc[m] * (xsa[m] * wsn);
        float* o = out + (size_t)m * NN + n4;
        unsafeAtomicAdd(o + 0, r.x);
        unsafeAtomicAdd(o + 1, r.y);
        unsafeAtomicAdd(o + 2, r.z);
        unsafeAtomicAdd(o + 3, r.w);
    }
}

extern "C" void kernel_launch(void* const* d_in, const int* in_sizes, int n_in,
                              void* d_out, int out_size, void* d_ws, size_t ws_size,
                              hipStream_t stream) {
    const float* x     = (const float*)d_in[0];   // [M,K] f32
    const float* W     = (const float*)d_in[1];   // [K,N] f32 (fp8 values)
    const float* wsinv = (const float*)d_in[2];   // [N]   f32
    const float* bias  = (const float*)d_in[3];   // [N]   f32
    float* out = (float*)d_out;                   // [M,N] f32
    float* ws  = (float*)d_ws;

    const size_t need = (size_t)(PART_OFF + (size_t)KSPLIT * MM * NN) * sizeof(float);

    prep_kernel<<<MM, 256, 0, stream>>>(x, ws);

    if (ws_size >= need) {
        float* part = ws + PART_OFF;
        gemm_partial<<<dim3(NN / 1024, KSPLIT), 256, 0, stream>>>(W, wsinv, ws, part);
        reduce_kernel<<<(MM * NN) / 256, 256, 0, stream>>>(part, bias, out);
    } else {
        init_kernel<<<(MM * NN) / 256, 256, 0, stream>>>(bias, out);
        gemm_atomic<<<dim3(NN / 1024, KSPLIT), 256, 0, stream>>>(W, wsinv, ws, out);
    }
}